// Round 3
// baseline (510.195 us; speedup 1.0000x reference)
//
#include <hip/hip_runtime.h>
#include <hip/hip_bf16.h>
#include <stdint.h>

#define N_ 4096
#define H_ 1024
#define V_ 16384

using i32x8  = __attribute__((ext_vector_type(8))) int;
using f32x16 = __attribute__((ext_vector_type(16))) float;

// 8 floats -> 8 fp8 e4m3 (OCP) per thread; both tensors in one launch
__global__ void cast2_f32_to_fp8(const float* __restrict__ in0, uint8_t* __restrict__ out0,
                                 const float* __restrict__ in1, uint8_t* __restrict__ out1,
                                 int nblk0) {
    const float* in;
    uint8_t* out;
    int bid;
    if (blockIdx.x < (unsigned)nblk0) { in = in0; out = out0; bid = blockIdx.x; }
    else                              { in = in1; out = out1; bid = blockIdx.x - nblk0; }
    size_t i = ((size_t)bid * blockDim.x + threadIdx.x) * 8;
    float4 a = *(const float4*)(in + i);
    float4 b = *(const float4*)(in + i + 4);
    int lo = __builtin_amdgcn_cvt_pk_fp8_f32(a.x, a.y, 0, 0);
    lo     = __builtin_amdgcn_cvt_pk_fp8_f32(a.z, a.w, lo, 1);
    int hi = __builtin_amdgcn_cvt_pk_fp8_f32(b.x, b.y, 0, 0);
    hi     = __builtin_amdgcn_cvt_pk_fp8_f32(b.z, b.w, hi, 1);
    *(int2*)(out + i) = make_int2(lo, hi);
}

#define BM 128
#define BN 128
#define BK 128

// C[m,v] = sum_k A[m,k]*W[v,k]; fused MSE partial per block.
// CHANGE vs prior round (single variable): B (W8) is NOT staged in LDS.
// With the XCD swizzle each XCD's W8 slice is 2 MB -> L2-resident, so B
// fragments are loaded directly global->VGPR in MFMA operand layout
// (row = lane&31, k = (lane>>5)*32 + 16B chunk) — bit-identical bytes to
// the old LDS path. This halves LDS read traffic (the measured top pipe:
// 2x wave-grid read amplification + DMA writes ~60us/CU demand) and halves
// the DMA write traffic; B's amplified traffic moves to the L2 pipe (~30us).
// A-side staging/swizzle is the verified 0-conflict layout, unchanged:
//   chunk = 16 rows x 64B; stage lane l -> row l>>2, k-quarter (l&3)^f(l>>2),
//   f(r)=(r+(r>>2))&3; fragment read slot = rl*4 + (kq ^ f(rl)).
// Pipeline: STAGE(t+1) before compute(t); vmcnt(0) only after the MFMA
// cluster; one raw s_barrier per K-tile. Target prefetched at t=6/7.
__global__ __launch_bounds__(256, 2) void gemm_mse(
    const uint8_t* __restrict__ A8,   // N x H fp8
    const uint8_t* __restrict__ W8,   // V x H fp8
    const float*  __restrict__ target,// N x V
    const float*  __restrict__ bias,  // V
    float* __restrict__ partials)     // one per block
{
    __shared__ __align__(16) uint8_t As[2][16384];   // double-buffered A tile
    __shared__ float red[4];

    const int tid  = threadIdx.x;
    const int w    = tid >> 6;        // wave 0..3
    const int lane = tid & 63;
    const int l32  = lane & 31;
    const int half = lane >> 5;       // k-half within one instruction's K=64
    const int wm   = w >> 1;          // 2x2 wave grid, 64x64 each
    const int wn   = w & 1;

    // XCD-aware tile mapping: 128 col-tiles x 32 row-tiles (4096 % 8 == 0)
    const int flat = blockIdx.x;
    const int xcd  = flat & 7;
    const int idx  = flat >> 3;                 // 0..511 per XCD
    const int tx   = xcd * 16 + (idx & 15);     // V tile 0..127
    const int ty   = idx >> 4;                  // N tile 0..31

    const int rowBase = ty * BM;  // N dim
    const int colBase = tx * BN;  // V dim

    f32x16 acc[2][2];
#pragma unroll
    for (int i = 0; i < 2; ++i)
#pragma unroll
        for (int j = 0; j < 2; ++j)
#pragma unroll
            for (int r = 0; r < 16; ++r) acc[i][j][r] = 0.f;

    // ---- staging lane params: 16 rows x 64B per 1KB chunk, swizzled 16B k-quarter
    const int ldrow = lane >> 2;                          // 0..15
    const int ldkq  = (lane & 3) ^ ((ldrow + (ldrow >> 2)) & 3);

    // ---- A fragment read offsets (lane-constant), conflict-free swizzled
    const int rl  = lane & 15;
    const int rcb = (lane >> 4) & 1;                      // which 16-row chunk
    const int fl  = (rl + (rl >> 2)) & 3;
    int aOff[2][2];
#pragma unroll
    for (int i = 0; i < 2; ++i)
#pragma unroll
        for (int c = 0; c < 2; ++c) {
            const int slot = rl * 4 + (((half << 1) + c) ^ fl);
            aOff[i][c] = ((wm * 2 + i) * 2 + rcb) * 1024 + slot * 16;
        }

    // ---- B direct-from-global (L2) pointers, MFMA operand layout
    //      lane reads row (colBase + wn*64 + j*32 + (lane&31)), k-bytes
    //      [(lane>>5)*32 + c*16) within each K=64 half.
    const uint8_t* pB[2];
#pragma unroll
    for (int j = 0; j < 2; ++j)
        pB[j] = W8 + (size_t)(colBase + wn * 64 + j * 32 + l32) * H_ + (half * 32);

    // bias loaded before the loop
    float biasj[2];
#pragma unroll
    for (int j = 0; j < 2; ++j) biasj[j] = bias[colBase + wn * 64 + j * 32 + l32];

    // stage one BK=128 A-tile into buffer buf: per wave 2 halves x 2 chunks
    auto STAGE = [&](int t, int buf) {
        const int kT = t * BK;
#pragma unroll
        for (int h = 0; h < 2; ++h) {
#pragma unroll
            for (int c = 0; c < 2; ++c) {
                const int cid  = w * 2 + c;               // wave-uniform 0..7
                const int kOff = kT + h * 64 + ldkq * 16;
                const uint8_t* ga = A8 + (size_t)(rowBase + cid * 16 + ldrow) * H_ + kOff;
                __builtin_amdgcn_global_load_lds(
                    (const __attribute__((address_space(1))) void*)ga,
                    (__attribute__((address_space(3))) void*)(&As[buf][0] + h * 8192 + cid * 1024),
                    16, 0, 0);
            }
        }
    };

    float tgt0[16][2], tgt1[16][2];   // target prefetch (static indexing only)

    // prologue: tile 0
    STAGE(0, 0);
    asm volatile("s_waitcnt vmcnt(0)" ::: "memory");
    __builtin_amdgcn_s_barrier();
    asm volatile("" ::: "memory");

    int cur = 0;
    for (int t = 0; t < 8; ++t) {      // 8 K-tiles of 128
        // B fragment loads for this tile: 8x int4 from L2 (compiler-counted vmcnt)
        int4 bg[2][2][2];              // [h][j][c], fully static indexing
#pragma unroll
        for (int h = 0; h < 2; ++h)
#pragma unroll
            for (int j = 0; j < 2; ++j)
#pragma unroll
                for (int c = 0; c < 2; ++c)
                    bg[h][j][c] = *(const int4*)(pB[j] + t * BK + h * 64 + c * 16);

        if (t < 7) STAGE(t + 1, cur ^ 1);   // A prefetch overlaps this tile's MFMAs
        asm volatile("" ::: "memory");
        if (t == 6) {
#pragma unroll
            for (int r = 0; r < 16; ++r) {
                const int row = (r & 3) + 8 * (r >> 2) + 4 * half;
                const float* trow = target + (size_t)(rowBase + wm * 64 + 0 * 32 + row) * V_
                                    + colBase + wn * 64 + l32;
                tgt0[r][0] = trow[0];
                tgt0[r][1] = trow[32];
            }
        }
        if (t == 7) {
#pragma unroll
            for (int r = 0; r < 16; ++r) {
                const int row = (r & 3) + 8 * (r >> 2) + 4 * half;
                const float* trow = target + (size_t)(rowBase + wm * 64 + 1 * 32 + row) * V_
                                    + colBase + wn * 64 + l32;
                tgt1[r][0] = trow[0];
                tgt1[r][1] = trow[32];
            }
        }

        const uint8_t* aB = &As[cur][0];
#pragma unroll
        for (int h = 0; h < 2; ++h) {
            i32x8 af[2], bq[2];
#pragma unroll
            for (int i = 0; i < 2; ++i) {
                int4 a0 = *(const int4*)(aB + h * 8192 + aOff[i][0]);
                int4 a1 = *(const int4*)(aB + h * 8192 + aOff[i][1]);
                af[i][0] = a0.x; af[i][1] = a0.y; af[i][2] = a0.z; af[i][3] = a0.w;
                af[i][4] = a1.x; af[i][5] = a1.y; af[i][6] = a1.z; af[i][7] = a1.w;
            }
#pragma unroll
            for (int j = 0; j < 2; ++j) {
                bq[j][0] = bg[h][j][0].x; bq[j][1] = bg[h][j][0].y;
                bq[j][2] = bg[h][j][0].z; bq[j][3] = bg[h][j][0].w;
                bq[j][4] = bg[h][j][1].x; bq[j][5] = bg[h][j][1].y;
                bq[j][6] = bg[h][j][1].z; bq[j][7] = bg[h][j][1].w;
            }
            __builtin_amdgcn_s_setprio(1);
#pragma unroll
            for (int i = 0; i < 2; ++i)
#pragma unroll
                for (int j = 0; j < 2; ++j)
                    acc[i][j] = __builtin_amdgcn_mfma_scale_f32_32x32x64_f8f6f4(
                        af[i], bq[j], acc[i][j],
                        0 /*cbsz: fp8 e4m3*/, 0 /*blgp: fp8 e4m3*/,
                        0, 0x7F7F7F7F,   // A scales: 2^0
                        0, 0x7F7F7F7F);  // B scales: 2^0
            __builtin_amdgcn_s_setprio(0);
        }

        if (t < 7) {
            // A staging for t+1 had the whole compute phase to land
            asm volatile("s_waitcnt vmcnt(0)" ::: "memory");
            __builtin_amdgcn_s_barrier();
            asm volatile("" ::: "memory");
        }
        cur ^= 1;
    }

    // epilogue: 32x32 C/D layout: col = l32, row = (r&3) + 8*(r>>2) + 4*half
    float sum = 0.f;
#pragma unroll
    for (int r = 0; r < 16; ++r) {
#pragma unroll
        for (int j = 0; j < 2; ++j) {
            float d = acc[0][j][r] + biasj[j] - tgt0[r][j];
            sum += d * d;
        }
    }
#pragma unroll
    for (int r = 0; r < 16; ++r) {
#pragma unroll
        for (int j = 0; j < 2; ++j) {
            float d = acc[1][j][r] + biasj[j] - tgt1[r][j];
            sum += d * d;
        }
    }

    // block reduction
#pragma unroll
    for (int off = 32; off; off >>= 1) sum += __shfl_down(sum, off, 64);
    if (lane == 0) red[w] = sum;
    __syncthreads();
    if (tid == 0)
        partials[flat] = red[0] + red[1] + red[2] + red[3];
}

__global__ void finalize_kernel(const float* __restrict__ partials, float* __restrict__ out, int n) {
    float s = 0.f;
    for (int i = threadIdx.x; i < n; i += 256) s += partials[i];
#pragma unroll
    for (int off = 32; off; off >>= 1) s += __shfl_down(s, off, 64);
    __shared__ float red[4];
    const int w = threadIdx.x >> 6, lane = threadIdx.x & 63;
    if (lane == 0) red[w] = s;
    __syncthreads();
    if (threadIdx.x == 0)
        out[0] = (red[0] + red[1] + red[2] + red[3]) * (1.0f / ((float)N_ * (float)V_));
}

extern "C" void kernel_launch(void* const* d_in, const int* in_sizes, int n_in,
                              void* d_out, int out_size, void* d_ws, size_t ws_size,
                              hipStream_t stream) {
    const float* input  = (const float*)d_in[0];  // N x H
    const float* weight = (const float*)d_in[1];  // V x H
    const float* target = (const float*)d_in[2];  // N x V
    const float* bias   = (const float*)d_in[3];  // V
    float* out = (float*)d_out;

    uint8_t* A8 = (uint8_t*)d_ws;                       // N*H fp8
    uint8_t* W8 = A8 + (size_t)N_ * H_;                 // V*H fp8
    float* partials = (float*)(W8 + (size_t)V_ * H_);   // 4096 floats

    const int nblk0 = (N_ * H_) / (256 * 8);            // 2048
    const int nblk1 = (V_ * H_) / (256 * 8);            // 8192
    cast2_f32_to_fp8<<<nblk0 + nblk1, 256, 0, stream>>>(input, A8, weight, W8, nblk0);

    const int nblocks = (V_ / BN) * (N_ / BM);          // 4096
    gemm_mse<<<nblocks, 256, 0, stream>>>(A8, W8, target, bias, partials);

    finalize_kernel<<<1, 256, 0, stream>>>(partials, out, nblocks);
}

// Round 5
// 455.683 us; speedup vs baseline: 1.1196x; 1.1196x over previous
//
#include <hip/hip_runtime.h>
#include <hip/hip_bf16.h>
#include <stdint.h>

#define N_ 4096
#define H_ 1024
#define V_ 16384

using i32x8  = __attribute__((ext_vector_type(8))) int;
using f32x16 = __attribute__((ext_vector_type(16))) float;

// 8 floats -> 8 fp8 e4m3 (OCP) per thread; both tensors in one launch
__global__ void cast2_f32_to_fp8(const float* __restrict__ in0, uint8_t* __restrict__ out0,
                                 const float* __restrict__ in1, uint8_t* __restrict__ out1,
                                 int nblk0) {
    const float* in;
    uint8_t* out;
    int bid;
    if (blockIdx.x < (unsigned)nblk0) { in = in0; out = out0; bid = blockIdx.x; }
    else                              { in = in1; out = out1; bid = blockIdx.x - nblk0; }
    size_t i = ((size_t)bid * blockDim.x + threadIdx.x) * 8;
    float4 a = *(const float4*)(in + i);
    float4 b = *(const float4*)(in + i + 4);
    int lo = __builtin_amdgcn_cvt_pk_fp8_f32(a.x, a.y, 0, 0);
    lo     = __builtin_amdgcn_cvt_pk_fp8_f32(a.z, a.w, lo, 1);
    int hi = __builtin_amdgcn_cvt_pk_fp8_f32(b.x, b.y, 0, 0);
    hi     = __builtin_amdgcn_cvt_pk_fp8_f32(b.z, b.w, hi, 1);
    *(int2*)(out + i) = make_int2(lo, hi);
}

#define BM 128
#define BN 128
#define BK 64    // 16 K-tiles; double-buffered -> 32 KB LDS -> 4 blocks/CU

// C[m,v] = sum_k A[m,k]*W[v,k]; fused MSE partial per block.
// R4 (re-run; prior submit hit GPUAcquisitionTimeout — never measured):
// B restored to the verified LDS path (R3's B-direct was latency-bound:
// MfmaUtil 14%, HBM 14%, scattered 32-line loads with no prefetch).
// Single lever this round: occupancy x pipelining together.
//   - BK=64 double-buffered: As+Bs = 32 KB -> 4 blocks/CU (R2's 64 KB gave 2).
//   - target prefetch dropped (cost 64 VGPR); with 4 resident blocks the
//     epilogue's target read hides under other blocks' compute (m114 overlap).
//   - __launch_bounds__(256,4) caps VGPR <= 128 so 16 waves/CU actually fit.
//   - pipeline kept: STAGE(t+1) before compute(t); vmcnt(0) only AFTER the
//     MFMA cluster; ONE raw s_barrier per K-tile.
// LDS chunk layout / swizzle identical to the verified kernel (0 conflicts):
//   chunk = 16 rows x 64B; stage lane l -> row l>>2, k-quarter (l&3)^f(l>>2),
//   f(r)=(r+(r>>2))&3; fragment read slot = rl*4 + (kq ^ f(rl)).
// With BK=64 each 1KB chunk covers the full K-range of a tile (no h halves).
__global__ __launch_bounds__(256, 4) void gemm_mse(
    const uint8_t* __restrict__ A8,   // N x H fp8
    const uint8_t* __restrict__ W8,   // V x H fp8
    const float*  __restrict__ target,// N x V
    const float*  __restrict__ bias,  // V
    float* __restrict__ partials)     // one per block
{
    __shared__ __align__(16) uint8_t As[2][8192];   // double-buffered A tile
    __shared__ __align__(16) uint8_t Bs[2][8192];   // double-buffered B tile
    __shared__ float red[4];

    const int tid  = threadIdx.x;
    const int w    = tid >> 6;        // wave 0..3
    const int lane = tid & 63;
    const int l32  = lane & 31;
    const int half = lane >> 5;       // k-half within one instruction's K=64
    const int wm   = w >> 1;          // 2x2 wave grid, 64x64 each
    const int wn   = w & 1;

    // XCD-aware tile mapping: 128 col-tiles x 32 row-tiles (4096 % 8 == 0)
    const int flat = blockIdx.x;
    const int xcd  = flat & 7;
    const int idx  = flat >> 3;                 // 0..511 per XCD
    const int tx   = xcd * 16 + (idx & 15);     // V tile 0..127
    const int ty   = idx >> 4;                  // N tile 0..31

    const int rowBase = ty * BM;  // N dim
    const int colBase = tx * BN;  // V dim

    f32x16 acc[2][2];
#pragma unroll
    for (int i = 0; i < 2; ++i)
#pragma unroll
        for (int j = 0; j < 2; ++j)
#pragma unroll
            for (int r = 0; r < 16; ++r) acc[i][j][r] = 0.f;

    // ---- staging lane params: 16 rows x 64B per 1KB chunk, swizzled 16B k-quarter
    const int ldrow = lane >> 2;                          // 0..15
    const int ldkq  = (lane & 3) ^ ((ldrow + (ldrow >> 2)) & 3);

    // ---- fragment read offsets (lane-constant), conflict-free swizzled
    const int rl  = lane & 15;
    const int rcb = (lane >> 4) & 1;                      // which 16-row chunk
    const int fl  = (rl + (rl >> 2)) & 3;
    int aOff[2][2], bOff[2][2];
#pragma unroll
    for (int i = 0; i < 2; ++i)
#pragma unroll
        for (int c = 0; c < 2; ++c) {
            const int slot = rl * 4 + (((half << 1) + c) ^ fl);
            aOff[i][c] = ((wm * 2 + i) * 2 + rcb) * 1024 + slot * 16;
            bOff[i][c] = ((wn * 2 + i) * 2 + rcb) * 1024 + slot * 16;
        }

    // bias loaded before the loop
    float biasj[2];
#pragma unroll
    for (int j = 0; j < 2; ++j) biasj[j] = bias[colBase + wn * 64 + j * 32 + l32];

    // stage one BK=64 tile into buffer buf: per wave 2 chunks x {A,B}
    auto STAGE = [&](int t, int buf) {
        const int kT = t * BK;
#pragma unroll
        for (int c = 0; c < 2; ++c) {
            const int cid  = w * 2 + c;               // wave-uniform 0..7
            const int kOff = kT + ldkq * 16;
            const uint8_t* ga = A8 + (size_t)(rowBase + cid * 16 + ldrow) * H_ + kOff;
            __builtin_amdgcn_global_load_lds(
                (const __attribute__((address_space(1))) void*)ga,
                (__attribute__((address_space(3))) void*)(&As[buf][0] + cid * 1024),
                16, 0, 0);
            const uint8_t* gb = W8 + (size_t)(colBase + cid * 16 + ldrow) * H_ + kOff;
            __builtin_amdgcn_global_load_lds(
                (const __attribute__((address_space(1))) void*)gb,
                (__attribute__((address_space(3))) void*)(&Bs[buf][0] + cid * 1024),
                16, 0, 0);
        }
    };

    // prologue: tile 0
    STAGE(0, 0);
    asm volatile("s_waitcnt vmcnt(0)" ::: "memory");
    __builtin_amdgcn_s_barrier();
    asm volatile("" ::: "memory");

    int cur = 0;
    for (int t = 0; t < 16; ++t) {     // 16 K-tiles of 64
        if (t < 15) STAGE(t + 1, cur ^ 1);   // prefetch overlaps this tile's MFMAs
        asm volatile("" ::: "memory");

        const uint8_t* aB = &As[cur][0];
        const uint8_t* bB = &Bs[cur][0];
        i32x8 af[2], bq[2];
#pragma unroll
        for (int i = 0; i < 2; ++i) {
            int4 a0 = *(const int4*)(aB + aOff[i][0]);
            int4 a1 = *(const int4*)(aB + aOff[i][1]);
            af[i][0] = a0.x; af[i][1] = a0.y; af[i][2] = a0.z; af[i][3] = a0.w;
            af[i][4] = a1.x; af[i][5] = a1.y; af[i][6] = a1.z; af[i][7] = a1.w;
            int4 b0 = *(const int4*)(bB + bOff[i][0]);
            int4 b1 = *(const int4*)(bB + bOff[i][1]);
            bq[i][0] = b0.x; bq[i][1] = b0.y; bq[i][2] = b0.z; bq[i][3] = b0.w;
            bq[i][4] = b1.x; bq[i][5] = b1.y; bq[i][6] = b1.z; bq[i][7] = b1.w;
        }
        __builtin_amdgcn_s_setprio(1);
#pragma unroll
        for (int i = 0; i < 2; ++i)
#pragma unroll
            for (int j = 0; j < 2; ++j)
                acc[i][j] = __builtin_amdgcn_mfma_scale_f32_32x32x64_f8f6f4(
                    af[i], bq[j], acc[i][j],
                    0 /*cbsz: fp8 e4m3*/, 0 /*blgp: fp8 e4m3*/,
                    0, 0x7F7F7F7F,   // A scales: 2^0
                    0, 0x7F7F7F7F);  // B scales: 2^0
        __builtin_amdgcn_s_setprio(0);

        if (t < 15) {
            // staging for t+1 had the whole compute phase to land
            asm volatile("s_waitcnt vmcnt(0)" ::: "memory");
            __builtin_amdgcn_s_barrier();
            asm volatile("" ::: "memory");
        }
        cur ^= 1;
    }

    // epilogue: 32x32 C/D layout: col = l32, row = (r&3) + 8*(r>>2) + 4*half
    // target read NOT prefetched: with 4 blocks/CU resident, other blocks'
    // compute hides this HBM read (m114 cross-block overlap).
    float sum = 0.f;
#pragma unroll
    for (int i = 0; i < 2; ++i) {
#pragma unroll
        for (int r = 0; r < 16; ++r) {
            const int row = (r & 3) + 8 * (r >> 2) + 4 * half;
            const int gm = rowBase + wm * 64 + i * 32 + row;
            const float* trow = target + (size_t)gm * V_ + colBase + wn * 64 + l32;
#pragma unroll
            for (int j = 0; j < 2; ++j) {
                float d = acc[i][j][r] + biasj[j] - trow[j * 32];
                sum += d * d;
            }
        }
    }

    // block reduction
#pragma unroll
    for (int off = 32; off; off >>= 1) sum += __shfl_down(sum, off, 64);
    if (lane == 0) red[w] = sum;
    __syncthreads();
    if (tid == 0)
        partials[flat] = red[0] + red[1] + red[2] + red[3];
}

__global__ void finalize_kernel(const float* __restrict__ partials, float* __restrict__ out, int n) {
    float s = 0.f;
    for (int i = threadIdx.x; i < n; i += 256) s += partials[i];
#pragma unroll
    for (int off = 32; off; off >>= 1) s += __shfl_down(s, off, 64);
    __shared__ float red[4];
    const int w = threadIdx.x >> 6, lane = threadIdx.x & 63;
    if (lane == 0) red[w] = s;
    __syncthreads();
    if (threadIdx.x == 0)
        out[0] = (red[0] + red[1] + red[2] + red[3]) * (1.0f / ((float)N_ * (float)V_));
}

extern "C" void kernel_launch(void* const* d_in, const int* in_sizes, int n_in,
                              void* d_out, int out_size, void* d_ws, size_t ws_size,
                              hipStream_t stream) {
    const float* input  = (const float*)d_in[0];  // N x H
    const float* weight = (const float*)d_in[1];  // V x H
    const float* target = (const float*)d_in[2];  // N x V
    const float* bias   = (const float*)d_in[3];  // V
    float* out = (float*)d_out;

    uint8_t* A8 = (uint8_t*)d_ws;                       // N*H fp8
    uint8_t* W8 = A8 + (size_t)N_ * H_;                 // V*H fp8
    float* partials = (float*)(W8 + (size_t)V_ * H_);   // 4096 floats

    const int nblk0 = (N_ * H_) / (256 * 8);            // 2048
    const int nblk1 = (V_ * H_) / (256 * 8);            // 8192
    cast2_f32_to_fp8<<<nblk0 + nblk1, 256, 0, stream>>>(input, A8, weight, W8, nblk0);

    const int nblocks = (V_ / BN) * (N_ / BM);          // 4096
    gemm_mse<<<nblocks, 256, 0, stream>>>(A8, W8, target, bias, partials);

    finalize_kernel<<<1, 256, 0, stream>>>(partials, out, nblocks);
}